// Round 4
// baseline (216.222 us; speedup 1.0000x reference)
//
#include <hip/hip_runtime.h>
#include <math.h>

#define NPTS 300000
#define K 64
#define P 32
#define DETC 1e-16f
// ws floats: [0,64) N_k | [64,128) S_k | [128,2176) M[d][k] | [2176] int counter
#define WS_FLOATS (K + K + K * P)

#define NTHREADS 256
#define WPB (NTHREADS / 64)
#define NTILES ((NPTS + 63) / 64)              // 4688 tiles of 64 points
#define NBLOCKS ((NTILES + WPB - 1) / WPB)     // 1172 -> exactly 1 tile per wave

// DPP add helper (bound_ctrl=1)
#define DPP_ADD(v, ctrl)                                                     \
    v += __int_as_float(__builtin_amdgcn_update_dpp(                         \
        0, __float_as_int(v), (ctrl), 0xF, 0xF, true))

__device__ __forceinline__ float rlf(float x, int l) {
    return __int_as_float(__builtin_amdgcn_readlane(__float_as_int(x), l));
}

// full wave-64 sum, total returned via lane 63
__device__ __forceinline__ float wave_sum64(float w) {
    float v = w;
    DPP_ADD(v, 0xB1);    // quad_perm xor1
    DPP_ADD(v, 0x4E);    // quad_perm xor2
    DPP_ADD(v, 0x128);   // row_ror:8
    DPP_ADD(v, 0x124);   // row_ror:4   -> every lane = its 16-row sum
    DPP_ADD(v, 0x142);   // row_bcast15
    DPP_ADD(v, 0x143);   // row_bcast31 -> lane63 = total
    return rlf(v, 63);
}

__global__ __launch_bounds__(NTHREADS, 4) void em_pass(
    const float* __restrict__ mu_phi,
    const float* __restrict__ log_cov_phi,
    const float* __restrict__ pi_k,
    const float* __restrict__ mu_k,
    const float* __restrict__ log_cov_k,
    float* __restrict__ gamma_out,
    float* __restrict__ out_tail,   // pi_new | mu_new | log_cov_new
    float* __restrict__ ws)
{
    const int lane = threadIdx.x & 63;                 // = cluster index
    const int wave = threadIdx.x >> 6;
    const int tile = __builtin_amdgcn_readfirstlane(blockIdx.x * WPB + wave);

    // ---- per-lane cluster constants ----
    float muk[P];
#pragma unroll
    for (int d = 0; d < P; ++d) muk[d] = mu_k[lane * P + d];
    const float lck  = log_cov_k[lane];
    const float icov = __expf(-lck);
    const float pik  = pi_k[lane];
    float n2k = 0.f;
#pragma unroll
    for (int d = 0; d < P; ++d) n2k = fmaf(muk[d], muk[d], n2k);
    // KL = Ak - 16*lcp + 0.5*icov*u - icov*dot ; w = pik*exp(-KL)
    const float Ak    = 0.5f * (32.f * lck - 32.f + icov * n2k) - __logf(pik);
    const float hicov = 0.5f * icov;

    float accN = 0.f, accS = 0.f;
    float accM[P];
#pragma unroll
    for (int d = 0; d < P; ++d) accM[d] = 0.f;

    if (tile < NTILES) {
        const int gb  = tile * 64;
        const int cnt = (NPTS - gb < 64) ? (NPTS - gb) : 64;

        // ---- u-phase: lane = point. Own row -> 32 VGPRs (register row cache) ----
        const int ip = gb + ((lane < cnt) ? lane : (cnt - 1));   // clamp, in-bounds
        float r[P];
        {
            const float4* r4 = reinterpret_cast<const float4*>(mu_phi + (size_t)ip * P);
            float4 a0 = r4[0], a1 = r4[1], a2 = r4[2], a3 = r4[3];
            float4 a4 = r4[4], a5 = r4[5], a6 = r4[6], a7 = r4[7];
#define PUT(j,q) r[4*j+0]=q.x; r[4*j+1]=q.y; r[4*j+2]=q.z; r[4*j+3]=q.w
            PUT(0,a0); PUT(1,a1); PUT(2,a2); PUT(3,a3);
            PUT(4,a4); PUT(5,a5); PUT(6,a6); PUT(7,a7);
#undef PUT
        }
        float n2 = 0.f;
#pragma unroll
        for (int d = 0; d < P; ++d) n2 = fmaf(r[d], r[d], n2);
        const float lcp = log_cov_phi[ip];
        const float u_v = fmaf(32.f, __expf(lcp), n2);   // P*e^lcp + ||phi||^2
        const float b_v = 16.f * lcp;

        // ---- per-point phase: lane = cluster. Row p broadcast from lane p's
        //      registers via v_readlane (dynamic lane) — NO memory in the loop ----
        for (int p = 0; p < cnt; ++p) {
            float sr[P];                                  // uniform -> SGPRs
#pragma unroll
            for (int d = 0; d < P; ++d) sr[d] = rlf(r[d], p);

            float d0 = 0.f, d1 = 0.f, d2 = 0.f, d3 = 0.f;
#pragma unroll
            for (int d = 0; d < P; d += 4) {
                d0 = fmaf(sr[d + 0], muk[d + 0], d0);
                d1 = fmaf(sr[d + 1], muk[d + 1], d1);
                d2 = fmaf(sr[d + 2], muk[d + 2], d2);
                d3 = fmaf(sr[d + 3], muk[d + 3], d3);
            }
            const float dot = (d0 + d1) + (d2 + d3);

            const float u_s = rlf(u_v, p);
            const float b_s = rlf(b_v, p);
            const float t = fmaf(-hicov, u_s, b_s) - Ak;
            const float w = __expf(fmaf(icov, dot, t));

            const float s = wave_sum64(w);
            const float g = fmaf(w, __builtin_amdgcn_rcpf(s), DETC);
            gamma_out[(size_t)(gb + p) * K + lane] = g;   // coalesced 256B

            accN += g;
            accS = fmaf(g, u_s, accS);
#pragma unroll
            for (int d = 0; d < P; ++d) accM[d] = fmaf(g, sr[d], accM[d]);
        }
    }

    // ---- block combine in LDS, then one set of global atomics ----
    __shared__ float lN[K], lS[K], lM[K * P];
    for (int idx = threadIdx.x; idx < K; idx += NTHREADS) { lN[idx] = 0.f; lS[idx] = 0.f; }
    for (int idx = threadIdx.x; idx < K * P; idx += NTHREADS) lM[idx] = 0.f;
    __syncthreads();

    atomicAdd(&lN[lane], accN);
    atomicAdd(&lS[lane], accS);
#pragma unroll
    for (int d = 0; d < P; ++d) atomicAdd(&lM[d * K + lane], accM[d]);
    __syncthreads();

    for (int idx = threadIdx.x; idx < K; idx += NTHREADS) {
        atomicAdd(&ws[idx], lN[idx]);
        atomicAdd(&ws[K + idx], lS[idx]);
    }
    for (int idx = threadIdx.x; idx < K * P; idx += NTHREADS)
        atomicAdd(&ws[2 * K + idx], lM[idx]);
    __syncthreads();

    // ---- decoupled finalize: last block computes the small outputs ----
    __shared__ int lastf;
    if (threadIdx.x == 0) {
        __threadfence();
        const int c = atomicAdd((int*)(ws + WS_FLOATS), 1);
        lastf = (c == NBLOCKS - 1);
    }
    __syncthreads();
    if (lastf) {
        __threadfence();
        const int k = threadIdx.x;
        if (k < K) {
            const float Nk = __hip_atomic_load(&ws[k],     __ATOMIC_RELAXED, __HIP_MEMORY_SCOPE_AGENT);
            const float S  = __hip_atomic_load(&ws[K + k], __ATOMIC_RELAXED, __HIP_MEMORY_SCOPE_AGENT);
            float* pi_new      = out_tail;
            float* mu_new      = out_tail + K;
            float* log_cov_new = out_tail + K + K * P;

            pi_new[k] = Nk / (float)NPTS;
            const float invN = 1.f / Nk;
            float m2 = 0.f;
#pragma unroll
            for (int d = 0; d < P; ++d) {
                const float md = __hip_atomic_load(&ws[2 * K + d * K + k],
                                                   __ATOMIC_RELAXED, __HIP_MEMORY_SCOPE_AGENT) * invN;
                mu_new[k * P + d] = md;
                m2 = fmaf(md, md, m2);
            }
            const float cov = (S - Nk * m2) / (32.f * Nk);
            log_cov_new[k] = logf(cov);
        }
    }
}

extern "C" void kernel_launch(void* const* d_in, const int* in_sizes, int n_in,
                              void* d_out, int out_size, void* d_ws, size_t ws_size,
                              hipStream_t stream)
{
    const float* mu_phi      = (const float*)d_in[0];
    const float* log_cov_phi = (const float*)d_in[1];
    const float* pi_k        = (const float*)d_in[2];
    const float* mu_k        = (const float*)d_in[3];
    const float* log_cov_k   = (const float*)d_in[4];
    float* out = (float*)d_out;
    float* ws  = (float*)d_ws;

    hipMemsetAsync(ws, 0, (WS_FLOATS + 1) * sizeof(float), stream);
    em_pass<<<NBLOCKS, NTHREADS, 0, stream>>>(mu_phi, log_cov_phi, pi_k, mu_k,
                                              log_cov_k, out,
                                              out + (size_t)NPTS * K, ws);
}